// Round 11
// baseline (57.430 us; speedup 1.0000x reference)
//
#include <hip/hip_runtime.h>
#include <hip/hip_fp8.h>

#define B_ROWS 4096
#define NTOT   8192
#define D0     256
#define D1     64
#define KDIM   320   // bytes per phi row (fp8, repacked order)
#define NSB    128   // prep blocks (64 rows each)
#define NTILE  64    // 8192 / 128
#define NTRI   2080  // NTILE*(NTILE+1)/2

typedef __attribute__((ext_vector_type(4))) float f32x4;
typedef __attribute__((ext_vector_type(2))) long long2v;

// workspace layout (bytes)
#define OFF_GAM   0        // 4 floats: g0, g1, g1/g0, 2*g0
#define OFF_PQ0   32       // 128 floats: per-block sum x^2 (dim0)
#define OFF_PQ1   544      // 128 floats: per-block sum x^2 (dim1)
#define OFF_P0    1056     // 128*256 floats: colsum partials dim0
#define OFF_P1    132128   // 128*64 floats: colsum partials dim1
#define OFF_R0    164896   // 8192 floats: ||x_hat||^2
#define OFF_R1    197664   // 8192 floats: ||y_hat||^2
#define OFF_BSUM  230432   // 2080 doubles
#define OFF_PHI   247072   // 8192*320 bytes (fp8), 16B aligned

__device__ __forceinline__ void load_lds16(const void* g, void* l) {
    __builtin_amdgcn_global_load_lds(
        (const __attribute__((address_space(1))) void*)g,
        (__attribute__((address_space(3))) void*)l, 16, 0, 0);
}

// ---------------- K1: fused prep = stats + UNSCALED fp8 pack + r0/r1 --------
// 128 blocks x 256 threads; block b owns rows b*64 .. b*64+63.
// Pack row byte order: orig k -> kk=k>>5, rg=(k>>3)&3, b=k&7
//                      new off = (kk>>1)*64 + rg*16 + (kk&1)*8 + b
__global__ __launch_bounds__(256) void k_prep(
    const float* __restrict__ s0, const float* __restrict__ s1,
    const float* __restrict__ t0, const float* __restrict__ t1,
    float* __restrict__ part0, float* __restrict__ part1,
    float* __restrict__ pq0, float* __restrict__ pq1,
    unsigned char* __restrict__ phi,
    float* __restrict__ r0vec, float* __restrict__ r1vec) {
    __shared__ float sh0[4][256];
    __shared__ float sh1[4][64];
    __shared__ float shq[4][2];
    int t = threadIdx.x, wv = t >> 6, lane = t & 63;
    int rb = blockIdx.x * 64;
    int c4 = lane * 4;
    int rr = wv;

    // ---- Phase A: column-sum partials + sum-of-squares (raw f32) ----
    f32x4 cs = {0.f, 0.f, 0.f, 0.f};
    float q0 = 0.f;
    #pragma unroll 4
    for (int k = 0; k < 16; ++k) {
        int row = rb + rr + k * 4;
        const float* b0 = (row < B_ROWS) ? s0 + (size_t)row * D0 : t0 + (size_t)(row - B_ROWS) * D0;
        f32x4 v = *(const f32x4*)(b0 + c4);
        cs.x += v.x; cs.y += v.y; cs.z += v.z; cs.w += v.w;
        q0 += v.x * v.x + v.y * v.y + v.z * v.z + v.w * v.w;
    }
    *(f32x4*)&sh0[rr][c4] = cs;

    float cs1 = 0.f, q1 = 0.f;
    #pragma unroll 4
    for (int k = 0; k < 16; ++k) {
        int row = rb + rr + k * 4;
        const float* b1 = (row < B_ROWS) ? s1 + (size_t)row * D1 : t1 + (size_t)(row - B_ROWS) * D1;
        float v = b1[lane];
        cs1 += v; q1 += v * v;
    }
    sh1[rr][lane] = cs1;

    #pragma unroll
    for (int o = 32; o; o >>= 1) { q0 += __shfl_xor(q0, o, 64); q1 += __shfl_xor(q1, o, 64); }
    if (lane == 0) { shq[wv][0] = q0; shq[wv][1] = q1; }
    __syncthreads();

    part0[blockIdx.x * D0 + t] = sh0[0][t] + sh0[1][t] + sh0[2][t] + sh0[3][t];
    if (t < D1) part1[blockIdx.x * D1 + t] = sh1[0][t] + sh1[1][t] + sh1[2][t] + sh1[3][t];
    if (t == 0) {
        pq0[blockIdx.x] = shq[0][0] + shq[1][0] + shq[2][0] + shq[3][0];
        pq1[blockIdx.x] = shq[0][1] + shq[1][1] + shq[2][1] + shq[3][1];
    }

    // ---- Phase B: pack 16 rows per wave, UNSCALED fp8; r from quantized ----
    for (int r = 0; r < 16; ++r) {
        int row = rb + wv * 16 + r;
        const float* b0p = (row < B_ROWS) ? s0 + (size_t)row * D0
                                          : t0 + (size_t)(row - B_ROWS) * D0;
        const float* b1p = (row < B_ROWS) ? s1 + (size_t)row * D1
                                          : t1 + (size_t)(row - B_ROWS) * D1;
        unsigned char* pr = phi + (size_t)row * KDIM;
        f32x4 v = *(const f32x4*)(b0p + lane * 4);
        __hip_fp8_e4m3 a0(v.x), a1(v.y), a2(v.z), a3(v.w);
        unsigned int word = (unsigned int)a0.__x | ((unsigned int)a1.__x << 8) |
                            ((unsigned int)a2.__x << 16) | ((unsigned int)a3.__x << 24);
        int doff0 = ((lane >> 4) << 6) + (((lane >> 1) & 3) << 4) +
                    (((lane >> 3) & 1) << 3) + ((lane & 1) << 2);
        *(unsigned int*)(pr + doff0) = word;
        float f0 = (float)a0, f1 = (float)a1, f2 = (float)a2, f3 = (float)a3;
        float p0 = f0 * f0 + f1 * f1 + f2 * f2 + f3 * f3;
        __hip_fp8_e4m3 qd(b1p[lane]);
        int doff1 = 256 + (((lane >> 3) & 3) << 4) + (((lane >> 5) & 1) << 3) + (lane & 7);
        pr[doff1] = qd.__x;
        float fd = (float)qd;
        float p1 = fd * fd;
        #pragma unroll
        for (int o = 32; o; o >>= 1) { p0 += __shfl_xor(p0, o, 64); p1 += __shfl_xor(p1, o, 64); }
        if (lane == 0) { r0vec[row] = p0; r1vec[row] = p1; }
    }
}

// ---------------- K2: gamma (single block, fp64 reduce) ----------------------
__global__ __launch_bounds__(256) void k_gamma(
    const float* __restrict__ pq0, const float* __restrict__ pq1,
    const float* __restrict__ part0, const float* __restrict__ part1,
    float* __restrict__ gam) {
    __shared__ double sh[4][4];
    int t = threadIdx.x, wv = t >> 6, lane = t & 63;

    double a0 = 0.0, a1 = 0.0;
    if (t < NSB) { a0 = (double)pq0[t]; a1 = (double)pq1[t]; }

    double F0t = 0.0;
    for (int b = 0; b < NSB; ++b) F0t += (double)part0[b * D0 + t];
    double nf0 = F0t * F0t;

    double nf1 = 0.0;
    if (t < D1) {
        double F1t = 0.0;
        for (int b = 0; b < NSB; ++b) F1t += (double)part1[b * D1 + t];
        nf1 = F1t * F1t;
    }

    #pragma unroll
    for (int o = 32; o; o >>= 1) {
        a0  += __shfl_xor(a0, o, 64);
        a1  += __shfl_xor(a1, o, 64);
        nf0 += __shfl_xor(nf0, o, 64);
        nf1 += __shfl_xor(nf1, o, 64);
    }
    if (lane == 0) { sh[wv][0] = a0; sh[wv][1] = a1; sh[wv][2] = nf0; sh[wv][3] = nf1; }
    __syncthreads();
    if (t == 0) {
        double b0 = 0, b1 = 0, b2 = 0, b3 = 0;
        for (int w = 0; w < 4; ++w) { b0 += sh[w][0]; b1 += sh[w][1]; b2 += sh[w][2]; b3 += sh[w][3]; }
        double n = (double)NTOT;
        double g0 = (n * n - n) / (2.0 * n * b0 - 2.0 * b2);
        double g1 = (n * n - n) / (2.0 * n * b1 - 2.0 * b3);
        gam[0] = (float)g0; gam[1] = (float)g1;
        gam[2] = (float)(g1 / g0); gam[3] = (float)(2.0 * g0);
    }
}

// ---------------- K3: fused Gram+exp+reduce (R5 structure + gamma-fold) ------
// 128x128 tile, 4 waves (64x64 each), K=320 in 2 stages, 48KB LDS, 3 barriers.
// Chunks 0-3 (dim0) -> acc; chunk 4 (dim1) -> tmp, folded as acc += ratio*tmp.
__global__ __launch_bounds__(256, 3) void k_mmd(
    const unsigned char* __restrict__ phi,
    const float* __restrict__ r0vec, const float* __restrict__ r1vec,
    const float* __restrict__ gam, double* __restrict__ blocksum) {
    // XCD swizzle (2080 % 8 == 0 -> bijective)
    int tb = (blockIdx.x & 7) * (NTRI / 8) + (blockIdx.x >> 3);
    int I = (int)((129.0f - sqrtf(16641.0f - 8.0f * (float)tb)) * 0.5f);
    while ((129 * I - I * I) / 2 > tb) --I;
    while ((129 * (I + 1) - (I + 1) * (I + 1)) / 2 <= tb) ++I;
    int J = I + (tb - (129 * I - I * I) / 2);

    __shared__ unsigned char As[24576];
    __shared__ unsigned char Bs[24576];
    __shared__ float wsum[4];

    int tid = threadIdx.x, wv = tid >> 6, lane = tid & 63;
    int wr = wv >> 1, wc = wv & 1;
    int rgrp = lane >> 4, rlow = lane & 15;
    const int rowA = I * 128, rowB = J * 128;

    const float g0 = gam[0], g1 = gam[1], ratio = gam[2], tg0 = gam[3];

    f32x4 acc_[4][4] = {};

    #define STAGE(tbase, nt)                                                    \
        _Pragma("unroll")                                                       \
        for (int it = 0; it < (nt) * 2; ++it) {                                 \
            int idx = it * 256 + tid;                                           \
            int tt = idx >> 9, rs = idx & 511;                                  \
            int row = rs >> 2, slot = rs & 3;                                   \
            int rg = slot ^ ((row >> 1) & 3);                                   \
            size_t gcol = ((tbase) + tt) * 64 + rg * 16;                        \
            load_lds16(phi + (size_t)(rowA + row) * KDIM + gcol,                \
                       As + it * 4096 + wv * 1024);                             \
            load_lds16(phi + (size_t)(rowB + row) * KDIM + gcol,                \
                       Bs + it * 4096 + wv * 1024);                             \
        }

    #define LOADFRAG(tt)                                                        \
        long2v af[4], bf[4];                                                    \
        _Pragma("unroll")                                                       \
        for (int m = 0; m < 4; ++m) {                                           \
            int row = wr * 64 + m * 16 + rlow;                                  \
            int sl = rgrp ^ ((row >> 1) & 3);                                   \
            af[m] = *(const long2v*)&As[(tt) * 8192 + row * 64 + sl * 16];      \
        }                                                                       \
        _Pragma("unroll")                                                       \
        for (int n = 0; n < 4; ++n) {                                           \
            int col = wc * 64 + n * 16 + rlow;                                  \
            int sl = rgrp ^ ((col >> 1) & 3);                                   \
            bf[n] = *(const long2v*)&Bs[(tt) * 8192 + col * 64 + sl * 16];      \
        }

    STAGE(0, 3);
    __syncthreads();
    #pragma unroll
    for (int tt = 0; tt < 3; ++tt) {
        LOADFRAG(tt);
        __builtin_amdgcn_s_setprio(1);
        #pragma unroll
        for (int m = 0; m < 4; ++m)
            #pragma unroll
            for (int n = 0; n < 4; ++n) {
                acc_[m][n] = __builtin_amdgcn_mfma_f32_16x16x32_fp8_fp8(
                    af[m][0], bf[n][0], acc_[m][n], 0, 0, 0);
                acc_[m][n] = __builtin_amdgcn_mfma_f32_16x16x32_fp8_fp8(
                    af[m][1], bf[n][1], acc_[m][n], 0, 0, 0);
            }
        __builtin_amdgcn_s_setprio(0);
    }
    __syncthreads();      // all reads of stage-1 LDS done before overwrite
    STAGE(3, 2);
    __syncthreads();
    {   // chunk 3 (dim0) -> acc
        LOADFRAG(0);
        __builtin_amdgcn_s_setprio(1);
        #pragma unroll
        for (int m = 0; m < 4; ++m)
            #pragma unroll
            for (int n = 0; n < 4; ++n) {
                acc_[m][n] = __builtin_amdgcn_mfma_f32_16x16x32_fp8_fp8(
                    af[m][0], bf[n][0], acc_[m][n], 0, 0, 0);
                acc_[m][n] = __builtin_amdgcn_mfma_f32_16x16x32_fp8_fp8(
                    af[m][1], bf[n][1], acc_[m][n], 0, 0, 0);
            }
        __builtin_amdgcn_s_setprio(0);
    }
    {   // chunk 4 (dim1) -> tmp, fold with ratio = g1/g0
        LOADFRAG(1);
        __builtin_amdgcn_s_setprio(1);
        #pragma unroll
        for (int m = 0; m < 4; ++m)
            #pragma unroll
            for (int n = 0; n < 4; ++n) {
                f32x4 tm = {0.f, 0.f, 0.f, 0.f};
                tm = __builtin_amdgcn_mfma_f32_16x16x32_fp8_fp8(
                    af[m][0], bf[n][0], tm, 0, 0, 0);
                tm = __builtin_amdgcn_mfma_f32_16x16x32_fp8_fp8(
                    af[m][1], bf[n][1], tm, 0, 0, 0);
                acc_[m][n] += ratio * tm;
            }
        __builtin_amdgcn_s_setprio(0);
    }

    // epilogue: e = 2*g0*acc - (g0*r0i+g1*r1i) - (g0*r0j+g1*r1j); sum exp
    float psum = 0.f;
    #pragma unroll
    for (int m = 0; m < 4; ++m) {
        int gi = rowA + wr * 64 + m * 16 + rgrp * 4;
        f32x4 r0i = *(const f32x4*)&r0vec[gi];
        f32x4 r1i = *(const f32x4*)&r1vec[gi];
        f32x4 ui = g0 * r0i + g1 * r1i;
        #pragma unroll
        for (int n = 0; n < 4; ++n) {
            int gj = rowB + wc * 64 + n * 16 + rlow;
            float uj = g0 * r0vec[gj] + g1 * r1vec[gj];
            f32x4 a = acc_[m][n];
            psum += __expf(tg0 * a.x - ui.x - uj);
            psum += __expf(tg0 * a.y - ui.y - uj);
            psum += __expf(tg0 * a.z - ui.z - uj);
            psum += __expf(tg0 * a.w - ui.w - uj);
        }
    }
    #pragma unroll
    for (int o = 32; o; o >>= 1) psum += __shfl_xor(psum, o, 64);
    if (lane == 0) wsum[wv] = psum;
    __syncthreads();
    if (tid == 0) {
        float bs = wsum[0] + wsum[1] + wsum[2] + wsum[3];
        double sgn = ((I < 32) == (J < 32)) ? 1.0 : -1.0;
        double fac = (I == J) ? 1.0 : 2.0;
        blocksum[tb] = sgn * fac * (double)bs;
    }
}

// ---------------- K4: finalize (reduce 2080 block sums) ----------------------
__global__ __launch_bounds__(256) void k_final(
    const double* __restrict__ blocksum, float* __restrict__ out) {
    __shared__ double sh[4];
    int t = threadIdx.x, wv = t >> 6, lane = t & 63;
    double s = 0.0;
    for (int i = t; i < NTRI; i += 256) s += blocksum[i];
    #pragma unroll
    for (int o = 32; o; o >>= 1) s += __shfl_xor(s, o, 64);
    if (lane == 0) sh[wv] = s;
    __syncthreads();
    if (t == 0) {
        double tot = sh[0] + sh[1] + sh[2] + sh[3];
        out[0] = (float)(tot / ((double)B_ROWS * (double)B_ROWS));
    }
}

extern "C" void kernel_launch(void* const* d_in, const int* in_sizes, int n_in,
                              void* d_out, int out_size, void* d_ws, size_t ws_size,
                              hipStream_t stream) {
    const float* s0 = (const float*)d_in[0];
    const float* s1 = (const float*)d_in[1];
    const float* t0 = (const float*)d_in[2];
    const float* t1 = (const float*)d_in[3];
    char* ws = (char*)d_ws;
    float*  gam  = (float*)(ws + OFF_GAM);
    float*  pq0  = (float*)(ws + OFF_PQ0);
    float*  pq1  = (float*)(ws + OFF_PQ1);
    float*  p0   = (float*)(ws + OFF_P0);
    float*  p1   = (float*)(ws + OFF_P1);
    float*  r0v  = (float*)(ws + OFF_R0);
    float*  r1v  = (float*)(ws + OFF_R1);
    double* bsum = (double*)(ws + OFF_BSUM);
    unsigned char* phi = (unsigned char*)(ws + OFF_PHI);

    k_prep<<<NSB, 256, 0, stream>>>(s0, s1, t0, t1, p0, p1, pq0, pq1, phi, r0v, r1v);
    k_gamma<<<1, 256, 0, stream>>>(pq0, pq1, p0, p1, gam);
    k_mmd<<<NTRI, 256, 0, stream>>>(phi, r0v, r1v, gam, bsum);
    k_final<<<1, 256, 0, stream>>>(bsum, (float*)d_out);
}

// Round 12
// 55.151 us; speedup vs baseline: 1.0413x; 1.0413x over previous
//
#include <hip/hip_runtime.h>
#include <hip/hip_fp8.h>

#define B_ROWS 4096
#define NTOT   8192
#define D0     256
#define D1     64
#define KDIM   320   // bytes per phi row (fp8, repacked order)
#define PB     256   // prep blocks (32 rows each)
#define NTILE  64    // 8192 / 128
#define NTRI   2080  // NTILE*(NTILE+1)/2

typedef __attribute__((ext_vector_type(4))) float f32x4;
typedef __attribute__((ext_vector_type(2))) long long2v;

// workspace layout (bytes)
#define OFF_GAM   0        // 4 floats: g0, g1, g1/g0, 2*g0
#define OFF_PQ0   16       // 256 floats: per-block sum x^2 (dim0)
#define OFF_PQ1   1040     // 256 floats: per-block sum x^2 (dim1)
#define OFF_P0    2064     // 256*256 floats: colsum partials dim0
#define OFF_P1    264208   // 256*64 floats: colsum partials dim1
#define OFF_R0    329744   // 8192 floats: ||x_hat||^2
#define OFF_R1    362512   // 8192 floats: ||y_hat||^2
#define OFF_BSUM  395280   // 2080 doubles
#define OFF_PHI   411920   // 8192*320 bytes (fp8), 16B aligned

__device__ __forceinline__ void load_lds16(const void* g, void* l) {
    __builtin_amdgcn_global_load_lds(
        (const __attribute__((address_space(1))) void*)g,
        (__attribute__((address_space(3))) void*)l, 16, 0, 0);
}

// ---------------- K1: single-pass prep = stats + UNSCALED fp8 pack + r ------
// 256 blocks x 256 threads; block b owns rows b*32 .. b*32+31 (8 rows/wave).
// Pack row byte order: orig k -> kk=k>>5, rg=(k>>3)&3, b=k&7
//                      new off = (kk>>1)*64 + rg*16 + (kk&1)*8 + b
__global__ __launch_bounds__(256) void k_prep(
    const float* __restrict__ s0, const float* __restrict__ s1,
    const float* __restrict__ t0, const float* __restrict__ t1,
    float* __restrict__ part0, float* __restrict__ part1,
    float* __restrict__ pq0, float* __restrict__ pq1,
    unsigned char* __restrict__ phi,
    float* __restrict__ r0vec, float* __restrict__ r1vec) {
    __shared__ float sh0[4][256];
    __shared__ float sh1[4][64];
    __shared__ float shq[4][2];
    int t = threadIdx.x, wv = t >> 6, lane = t & 63;
    int rb = blockIdx.x * 32;

    int doff0 = ((lane >> 4) << 6) + (((lane >> 1) & 3) << 4) +
                (((lane >> 3) & 1) << 3) + ((lane & 1) << 2);
    int doff1 = 256 + (((lane >> 3) & 3) << 4) + (((lane >> 5) & 1) << 3) + (lane & 7);

    f32x4 cs0 = {0.f, 0.f, 0.f, 0.f};
    float q0 = 0.f, cs1 = 0.f, q1 = 0.f;

    for (int r = 0; r < 8; ++r) {
        int row = rb + wv * 8 + r;
        const float* b0p = (row < B_ROWS) ? s0 + (size_t)row * D0
                                          : t0 + (size_t)(row - B_ROWS) * D0;
        const float* b1p = (row < B_ROWS) ? s1 + (size_t)row * D1
                                          : t1 + (size_t)(row - B_ROWS) * D1;
        unsigned char* pr = phi + (size_t)row * KDIM;

        f32x4 v = *(const f32x4*)(b0p + lane * 4);
        // raw stats (gamma must match reference's raw-f32 dist sum)
        cs0.x += v.x; cs0.y += v.y; cs0.z += v.z; cs0.w += v.w;
        q0 += v.x * v.x + v.y * v.y + v.z * v.z + v.w * v.w;
        // quantize + pack
        __hip_fp8_e4m3 a0(v.x), a1(v.y), a2(v.z), a3(v.w);
        unsigned int word = (unsigned int)a0.__x | ((unsigned int)a1.__x << 8) |
                            ((unsigned int)a2.__x << 16) | ((unsigned int)a3.__x << 24);
        *(unsigned int*)(pr + doff0) = word;
        float f0 = (float)a0, f1 = (float)a1, f2 = (float)a2, f3 = (float)a3;
        float p0 = f0 * f0 + f1 * f1 + f2 * f2 + f3 * f3;

        float w1 = b1p[lane];
        cs1 += w1; q1 += w1 * w1;
        __hip_fp8_e4m3 qd(w1);
        pr[doff1] = qd.__x;
        float fd = (float)qd;
        float p1 = fd * fd;

        #pragma unroll
        for (int o = 32; o; o >>= 1) { p0 += __shfl_xor(p0, o, 64); p1 += __shfl_xor(p1, o, 64); }
        if (lane == 0) { r0vec[row] = p0; r1vec[row] = p1; }
    }

    // block-level stats combine
    *(f32x4*)&sh0[wv][lane * 4] = cs0;
    sh1[wv][lane] = cs1;
    #pragma unroll
    for (int o = 32; o; o >>= 1) { q0 += __shfl_xor(q0, o, 64); q1 += __shfl_xor(q1, o, 64); }
    if (lane == 0) { shq[wv][0] = q0; shq[wv][1] = q1; }
    __syncthreads();
    part0[blockIdx.x * D0 + t] = sh0[0][t] + sh0[1][t] + sh0[2][t] + sh0[3][t];
    if (t < D1) part1[blockIdx.x * D1 + t] = sh1[0][t] + sh1[1][t] + sh1[2][t] + sh1[3][t];
    if (t == 0) {
        pq0[blockIdx.x] = shq[0][0] + shq[1][0] + shq[2][0] + shq[3][0];
        pq1[blockIdx.x] = shq[0][1] + shq[1][1] + shq[2][1] + shq[3][1];
    }
}

// ---------------- K2: gamma (single block, fp64 reduce) ----------------------
__global__ __launch_bounds__(256) void k_gamma(
    const float* __restrict__ pq0, const float* __restrict__ pq1,
    const float* __restrict__ part0, const float* __restrict__ part1,
    float* __restrict__ gam) {
    __shared__ double sh[4][4];
    int t = threadIdx.x, wv = t >> 6, lane = t & 63;

    double a0 = (double)pq0[t], a1 = (double)pq1[t];

    double F0t = 0.0;
    for (int b = 0; b < PB; ++b) F0t += (double)part0[b * D0 + t];
    double nf0 = F0t * F0t;

    double nf1 = 0.0;
    if (t < D1) {
        double F1t = 0.0;
        for (int b = 0; b < PB; ++b) F1t += (double)part1[b * D1 + t];
        nf1 = F1t * F1t;
    }

    #pragma unroll
    for (int o = 32; o; o >>= 1) {
        a0  += __shfl_xor(a0, o, 64);
        a1  += __shfl_xor(a1, o, 64);
        nf0 += __shfl_xor(nf0, o, 64);
        nf1 += __shfl_xor(nf1, o, 64);
    }
    if (lane == 0) { sh[wv][0] = a0; sh[wv][1] = a1; sh[wv][2] = nf0; sh[wv][3] = nf1; }
    __syncthreads();
    if (t == 0) {
        double b0 = 0, b1 = 0, b2 = 0, b3 = 0;
        for (int w = 0; w < 4; ++w) { b0 += sh[w][0]; b1 += sh[w][1]; b2 += sh[w][2]; b3 += sh[w][3]; }
        double n = (double)NTOT;
        double g0 = (n * n - n) / (2.0 * n * b0 - 2.0 * b2);
        double g1 = (n * n - n) / (2.0 * n * b1 - 2.0 * b3);
        gam[0] = (float)g0; gam[1] = (float)g1;
        gam[2] = (float)(g1 / g0); gam[3] = (float)(2.0 * g0);
    }
}

// ---------------- K3: fused Gram+exp+reduce (R5 structure + gamma-fold) ------
// 128x128 tile, 4 waves (64x64 each), K=320 in 2 stages, 48KB LDS, 3 barriers.
// Chunks 0-3 (dim0) -> acc; chunk 4 (dim1) -> tmp, folded as acc += ratio*tmp.
__global__ __launch_bounds__(256, 3) void k_mmd(
    const unsigned char* __restrict__ phi,
    const float* __restrict__ r0vec, const float* __restrict__ r1vec,
    const float* __restrict__ gam, double* __restrict__ blocksum) {
    // XCD swizzle (2080 % 8 == 0 -> bijective)
    int tb = (blockIdx.x & 7) * (NTRI / 8) + (blockIdx.x >> 3);
    int I = (int)((129.0f - sqrtf(16641.0f - 8.0f * (float)tb)) * 0.5f);
    while ((129 * I - I * I) / 2 > tb) --I;
    while ((129 * (I + 1) - (I + 1) * (I + 1)) / 2 <= tb) ++I;
    int J = I + (tb - (129 * I - I * I) / 2);

    __shared__ unsigned char As[24576];
    __shared__ unsigned char Bs[24576];
    __shared__ float uIl[128], uJl[128];
    __shared__ float wsum[4];

    int tid = threadIdx.x, wv = tid >> 6, lane = tid & 63;
    int wr = wv >> 1, wc = wv & 1;
    int rgrp = lane >> 4, rlow = lane & 15;
    const int rowA = I * 128, rowB = J * 128;

    const float g0 = gam[0], g1 = gam[1], ratio = gam[2], tg0 = gam[3];

    if (tid < 128) uIl[tid] = g0 * r0vec[rowA + tid] + g1 * r1vec[rowA + tid];
    else           uJl[tid - 128] = g0 * r0vec[rowB + (tid - 128)] +
                                    g1 * r1vec[rowB + (tid - 128)];

    f32x4 acc_[4][4] = {};

    #define STAGE(tbase, nt)                                                    \
        _Pragma("unroll")                                                       \
        for (int it = 0; it < (nt) * 2; ++it) {                                 \
            int idx = it * 256 + tid;                                           \
            int tt = idx >> 9, rs = idx & 511;                                  \
            int row = rs >> 2, slot = rs & 3;                                   \
            int rg = slot ^ ((row >> 1) & 3);                                   \
            size_t gcol = ((tbase) + tt) * 64 + rg * 16;                        \
            load_lds16(phi + (size_t)(rowA + row) * KDIM + gcol,                \
                       As + it * 4096 + wv * 1024);                             \
            load_lds16(phi + (size_t)(rowB + row) * KDIM + gcol,                \
                       Bs + it * 4096 + wv * 1024);                             \
        }

    #define LOADFRAG(tt)                                                        \
        long2v af[4], bf[4];                                                    \
        _Pragma("unroll")                                                       \
        for (int m = 0; m < 4; ++m) {                                           \
            int row = wr * 64 + m * 16 + rlow;                                  \
            int sl = rgrp ^ ((row >> 1) & 3);                                   \
            af[m] = *(const long2v*)&As[(tt) * 8192 + row * 64 + sl * 16];      \
        }                                                                       \
        _Pragma("unroll")                                                       \
        for (int n = 0; n < 4; ++n) {                                           \
            int col = wc * 64 + n * 16 + rlow;                                  \
            int sl = rgrp ^ ((col >> 1) & 3);                                   \
            bf[n] = *(const long2v*)&Bs[(tt) * 8192 + col * 64 + sl * 16];      \
        }

    STAGE(0, 3);
    __syncthreads();
    #pragma unroll
    for (int tt = 0; tt < 3; ++tt) {
        LOADFRAG(tt);
        __builtin_amdgcn_s_setprio(1);
        #pragma unroll
        for (int m = 0; m < 4; ++m)
            #pragma unroll
            for (int n = 0; n < 4; ++n) {
                acc_[m][n] = __builtin_amdgcn_mfma_f32_16x16x32_fp8_fp8(
                    af[m][0], bf[n][0], acc_[m][n], 0, 0, 0);
                acc_[m][n] = __builtin_amdgcn_mfma_f32_16x16x32_fp8_fp8(
                    af[m][1], bf[n][1], acc_[m][n], 0, 0, 0);
            }
        __builtin_amdgcn_s_setprio(0);
    }
    __syncthreads();      // all reads of stage-1 LDS done before overwrite
    STAGE(3, 2);
    __syncthreads();
    {   // chunk 3 (dim0) -> acc
        LOADFRAG(0);
        __builtin_amdgcn_s_setprio(1);
        #pragma unroll
        for (int m = 0; m < 4; ++m)
            #pragma unroll
            for (int n = 0; n < 4; ++n) {
                acc_[m][n] = __builtin_amdgcn_mfma_f32_16x16x32_fp8_fp8(
                    af[m][0], bf[n][0], acc_[m][n], 0, 0, 0);
                acc_[m][n] = __builtin_amdgcn_mfma_f32_16x16x32_fp8_fp8(
                    af[m][1], bf[n][1], acc_[m][n], 0, 0, 0);
            }
        __builtin_amdgcn_s_setprio(0);
    }
    {   // chunk 4 (dim1) -> tmp, fold with ratio = g1/g0
        LOADFRAG(1);
        __builtin_amdgcn_s_setprio(1);
        #pragma unroll
        for (int m = 0; m < 4; ++m)
            #pragma unroll
            for (int n = 0; n < 4; ++n) {
                f32x4 tm = {0.f, 0.f, 0.f, 0.f};
                tm = __builtin_amdgcn_mfma_f32_16x16x32_fp8_fp8(
                    af[m][0], bf[n][0], tm, 0, 0, 0);
                tm = __builtin_amdgcn_mfma_f32_16x16x32_fp8_fp8(
                    af[m][1], bf[n][1], tm, 0, 0, 0);
                acc_[m][n] += ratio * tm;
            }
        __builtin_amdgcn_s_setprio(0);
    }

    // epilogue: e = 2*g0*acc - u_i - u_j; sum exp
    float psum = 0.f;
    #pragma unroll
    for (int m = 0; m < 4; ++m) {
        float ui[4];
        #pragma unroll
        for (int j = 0; j < 4; ++j) ui[j] = uIl[wr * 64 + m * 16 + rgrp * 4 + j];
        #pragma unroll
        for (int n = 0; n < 4; ++n) {
            float uj = uJl[wc * 64 + n * 16 + rlow];
            f32x4 a = acc_[m][n];
            psum += __expf(tg0 * a.x - ui[0] - uj);
            psum += __expf(tg0 * a.y - ui[1] - uj);
            psum += __expf(tg0 * a.z - ui[2] - uj);
            psum += __expf(tg0 * a.w - ui[3] - uj);
        }
    }
    #pragma unroll
    for (int o = 32; o; o >>= 1) psum += __shfl_xor(psum, o, 64);
    if (lane == 0) wsum[wv] = psum;
    __syncthreads();
    if (tid == 0) {
        float bs = wsum[0] + wsum[1] + wsum[2] + wsum[3];
        double sgn = ((I < 32) == (J < 32)) ? 1.0 : -1.0;
        double fac = (I == J) ? 1.0 : 2.0;
        blocksum[tb] = sgn * fac * (double)bs;
    }
}

// ---------------- K4: finalize (reduce 2080 block sums) ----------------------
__global__ __launch_bounds__(256) void k_final(
    const double* __restrict__ blocksum, float* __restrict__ out) {
    __shared__ double sh[4];
    int t = threadIdx.x, wv = t >> 6, lane = t & 63;
    double s = 0.0;
    for (int i = t; i < NTRI; i += 256) s += blocksum[i];
    #pragma unroll
    for (int o = 32; o; o >>= 1) s += __shfl_xor(s, o, 64);
    if (lane == 0) sh[wv] = s;
    __syncthreads();
    if (t == 0) {
        double tot = sh[0] + sh[1] + sh[2] + sh[3];
        out[0] = (float)(tot / ((double)B_ROWS * (double)B_ROWS));
    }
}

extern "C" void kernel_launch(void* const* d_in, const int* in_sizes, int n_in,
                              void* d_out, int out_size, void* d_ws, size_t ws_size,
                              hipStream_t stream) {
    const float* s0 = (const float*)d_in[0];
    const float* s1 = (const float*)d_in[1];
    const float* t0 = (const float*)d_in[2];
    const float* t1 = (const float*)d_in[3];
    char* ws = (char*)d_ws;
    float*  gam  = (float*)(ws + OFF_GAM);
    float*  pq0  = (float*)(ws + OFF_PQ0);
    float*  pq1  = (float*)(ws + OFF_PQ1);
    float*  p0   = (float*)(ws + OFF_P0);
    float*  p1   = (float*)(ws + OFF_P1);
    float*  r0v  = (float*)(ws + OFF_R0);
    float*  r1v  = (float*)(ws + OFF_R1);
    double* bsum = (double*)(ws + OFF_BSUM);
    unsigned char* phi = (unsigned char*)(ws + OFF_PHI);

    k_prep<<<PB, 256, 0, stream>>>(s0, s1, t0, t1, p0, p1, pq0, pq1, phi, r0v, r1v);
    k_gamma<<<1, 256, 0, stream>>>(pq0, pq1, p0, p1, gam);
    k_mmd<<<NTRI, 256, 0, stream>>>(phi, r0v, r1v, gam, bsum);
    k_final<<<1, 256, 0, stream>>>(bsum, (float*)d_out);
}

// Round 13
// 52.885 us; speedup vs baseline: 1.0859x; 1.0428x over previous
//
#include <hip/hip_runtime.h>
#include <hip/hip_fp8.h>

#define B_ROWS 4096
#define NTOT   8192
#define D0     256
#define D1     64
#define KDIM   320   // bytes per phi row (fp8, repacked order)
#define NSB    128   // stats blocks (64 rows each)
#define NTILE  64    // 8192 / 128
#define NTRI   2080  // NTILE*(NTILE+1)/2
#define PERS   768   // persistent k_mmd blocks (3 per CU)

typedef __attribute__((ext_vector_type(4))) float f32x4;
typedef __attribute__((ext_vector_type(2))) long long2v;

// workspace layout (bytes)
#define OFF_GAM   0        // 4 floats
#define OFF_PQ0   32       // 128 floats: per-block sum x^2 (dim0)
#define OFF_PQ1   544      // 128 floats: per-block sum x^2 (dim1)
#define OFF_P0    1056     // 128*256 floats: colsum partials dim0
#define OFF_P1    132128   // 128*64 floats: colsum partials dim1
#define OFF_R     164896   // 8192 floats
#define OFF_BSUM  197664   // 2080 doubles
#define OFF_PHI   214304   // 8192*320 bytes (fp8), 16B aligned

__device__ __forceinline__ void load_lds16(const void* g, void* l) {
    __builtin_amdgcn_global_load_lds(
        (const __attribute__((address_space(1))) void*)g,
        (__attribute__((address_space(3))) void*)l, 16, 0, 0);
}

// ---------------- K1: fused stats (colsum partials + sum-of-squares) --------
__global__ __launch_bounds__(256) void k_stats(
    const float* __restrict__ s0, const float* __restrict__ s1,
    const float* __restrict__ t0, const float* __restrict__ t1,
    float* __restrict__ part0, float* __restrict__ part1,
    float* __restrict__ pq0, float* __restrict__ pq1) {
    __shared__ float sh0[4][256];
    __shared__ float sh1[4][64];
    __shared__ float shq[4][2];
    int t = threadIdx.x, wv = t >> 6, lane = t & 63;
    int rb = blockIdx.x * 64;
    int c4 = lane * 4;
    int rr = wv;

    f32x4 cs = {0.f, 0.f, 0.f, 0.f};
    float q0 = 0.f;
    #pragma unroll 4
    for (int k = 0; k < 16; ++k) {
        int row = rb + rr + k * 4;
        const float* b0 = (row < B_ROWS) ? s0 + (size_t)row * D0 : t0 + (size_t)(row - B_ROWS) * D0;
        f32x4 v = *(const f32x4*)(b0 + c4);
        cs.x += v.x; cs.y += v.y; cs.z += v.z; cs.w += v.w;
        q0 += v.x * v.x + v.y * v.y + v.z * v.z + v.w * v.w;
    }
    *(f32x4*)&sh0[rr][c4] = cs;

    float cs1 = 0.f, q1 = 0.f;
    #pragma unroll 4
    for (int k = 0; k < 16; ++k) {
        int row = rb + rr + k * 4;
        const float* b1 = (row < B_ROWS) ? s1 + (size_t)row * D1 : t1 + (size_t)(row - B_ROWS) * D1;
        float v = b1[lane];
        cs1 += v; q1 += v * v;
    }
    sh1[rr][lane] = cs1;

    #pragma unroll
    for (int o = 32; o; o >>= 1) { q0 += __shfl_xor(q0, o, 64); q1 += __shfl_xor(q1, o, 64); }
    if (lane == 0) { shq[wv][0] = q0; shq[wv][1] = q1; }
    __syncthreads();

    part0[blockIdx.x * D0 + t] = sh0[0][t] + sh0[1][t] + sh0[2][t] + sh0[3][t];
    if (t < D1) part1[blockIdx.x * D1 + t] = sh1[0][t] + sh1[1][t] + sh1[2][t] + sh1[3][t];
    if (t == 0) {
        pq0[blockIdx.x] = shq[0][0] + shq[1][0] + shq[2][0] + shq[3][0];
        pq1[blockIdx.x] = shq[0][1] + shq[1][1] + shq[2][1] + shq[3][1];
    }
}

// ---------------- K2: gamma (single block, fp64 reduce) ----------------------
__global__ __launch_bounds__(256) void k_gamma(
    const float* __restrict__ pq0, const float* __restrict__ pq1,
    const float* __restrict__ part0, const float* __restrict__ part1,
    float* __restrict__ gam) {
    __shared__ double sh[4][4];
    int t = threadIdx.x, wv = t >> 6, lane = t & 63;

    double a0 = 0.0, a1 = 0.0;
    if (t < NSB) { a0 = (double)pq0[t]; a1 = (double)pq1[t]; }

    double F0t = 0.0;
    for (int b = 0; b < NSB; ++b) F0t += (double)part0[b * D0 + t];
    double nf0 = F0t * F0t;

    double nf1 = 0.0;
    if (t < D1) {
        double F1t = 0.0;
        for (int b = 0; b < NSB; ++b) F1t += (double)part1[b * D1 + t];
        nf1 = F1t * F1t;
    }

    #pragma unroll
    for (int o = 32; o; o >>= 1) {
        a0  += __shfl_xor(a0, o, 64);
        a1  += __shfl_xor(a1, o, 64);
        nf0 += __shfl_xor(nf0, o, 64);
        nf1 += __shfl_xor(nf1, o, 64);
    }
    if (lane == 0) { sh[wv][0] = a0; sh[wv][1] = a1; sh[wv][2] = nf0; sh[wv][3] = nf1; }
    __syncthreads();
    if (t == 0) {
        double b0 = 0, b1 = 0, b2 = 0, b3 = 0;
        for (int w = 0; w < 4; ++w) { b0 += sh[w][0]; b1 += sh[w][1]; b2 += sh[w][2]; b3 += sh[w][3]; }
        double n = (double)NTOT;
        double g0 = (n * n - n) / (2.0 * n * b0 - 2.0 * b2);
        double g1 = (n * n - n) / (2.0 * n * b1 - 2.0 * b3);
        gam[0] = (float)g0; gam[1] = (float)g1;
        gam[2] = (float)sqrt(g0); gam[3] = (float)sqrt(g1);
    }
}

// ---------------- K3: pack scaled fp8 (REPACKED row order) + r ---------------
// Row byte order: orig k -> kk=k>>5, rg=(k>>3)&3, b=k&7
//                 new off = (kk>>1)*64 + rg*16 + (kk&1)*8 + b
__global__ __launch_bounds__(256) void k_pack(
    const float* __restrict__ s0, const float* __restrict__ s1,
    const float* __restrict__ t0, const float* __restrict__ t1,
    const float* __restrict__ gam, unsigned char* __restrict__ phi,
    float* __restrict__ rvec) {
    int wv = threadIdx.x >> 6, lane = threadIdx.x & 63;
    int row = blockIdx.x * 4 + wv;
    float sg0 = gam[2], sg1 = gam[3];
    const float* b0 = (row < B_ROWS) ? s0 + (size_t)row * D0 : t0 + (size_t)(row - B_ROWS) * D0;
    const float* b1 = (row < B_ROWS) ? s1 + (size_t)row * D1 : t1 + (size_t)(row - B_ROWS) * D1;
    unsigned char* pr = phi + (size_t)row * KDIM;
    f32x4 v = *(const f32x4*)(b0 + lane * 4);
    __hip_fp8_e4m3 q0(v.x * sg0), q1(v.y * sg0), q2(v.z * sg0), q3(v.w * sg0);
    unsigned int word = (unsigned int)q0.__x | ((unsigned int)q1.__x << 8) |
                        ((unsigned int)q2.__x << 16) | ((unsigned int)q3.__x << 24);
    int doff0 = ((lane >> 4) << 6) + (((lane >> 1) & 3) << 4) +
                (((lane >> 3) & 1) << 3) + ((lane & 1) << 2);
    *(unsigned int*)(pr + doff0) = word;
    float f0 = (float)q0, f1 = (float)q1, f2 = (float)q2, f3 = (float)q3;
    float p = f0 * f0 + f1 * f1 + f2 * f2 + f3 * f3;
    __hip_fp8_e4m3 qd(b1[lane] * sg1);
    int doff1 = 256 + (((lane >> 3) & 3) << 4) + (((lane >> 5) & 1) << 3) + (lane & 7);
    pr[doff1] = qd.__x;
    float fd = (float)qd;
    p += fd * fd;
    #pragma unroll
    for (int o = 32; o; o >>= 1) p += __shfl_xor(p, o, 64);
    if (lane == 0) rvec[row] = p;   // r_i = ||phi_hat_i||^2 (exact wrt quantized)
}

// ---------------- K4: PERSISTENT fused Gram+exp+reduce -----------------------
// 768 blocks (3/CU), each grid-strides over ~2.7 tiles. R5-verified inner
// schedule per tile; next tile's chunk0-2 stage issued under the epilogue.
__global__ __launch_bounds__(256, 3) void k_mmd(
    const unsigned char* __restrict__ phi, const float* __restrict__ rvec,
    double* __restrict__ blocksum) {
    __shared__ unsigned char As[24576];
    __shared__ unsigned char Bs[24576];
    __shared__ float rIl[128], rJl[128];
    __shared__ float wsum[4];

    int tid = threadIdx.x, wv = tid >> 6, lane = tid & 63;
    int wr = wv >> 1, wc = wv & 1;
    int rgrp = lane >> 4, rlow = lane & 15;

    #define DECODE(tb_, I_, J_)                                                 \
        I_ = (int)((129.0f - sqrtf(16641.0f - 8.0f * (float)(tb_))) * 0.5f);    \
        while ((129 * I_ - I_ * I_) / 2 > (tb_)) --I_;                          \
        while ((129 * (I_ + 1) - (I_ + 1) * (I_ + 1)) / 2 <= (tb_)) ++I_;       \
        J_ = I_ + ((tb_) - (129 * I_ - I_ * I_) / 2);

    #define STAGE(tbase, nt, ra, rb)                                            \
        _Pragma("unroll")                                                       \
        for (int it = 0; it < (nt) * 2; ++it) {                                 \
            int idx = it * 256 + tid;                                           \
            int tt = idx >> 9, rs = idx & 511;                                  \
            int row = rs >> 2, slot = rs & 3;                                   \
            int rg = slot ^ ((row >> 1) & 3);                                   \
            size_t gcol = ((tbase) + tt) * 64 + rg * 16;                        \
            load_lds16(phi + (size_t)((ra) + row) * KDIM + gcol,                \
                       As + it * 4096 + wv * 1024);                             \
            load_lds16(phi + (size_t)((rb) + row) * KDIM + gcol,                \
                       Bs + it * 4096 + wv * 1024);                             \
        }

    #define COMPUTE(nt)                                                         \
        _Pragma("unroll")                                                       \
        for (int tt = 0; tt < (nt); ++tt) {                                     \
            long2v af[4], bf[4];                                                \
            _Pragma("unroll")                                                   \
            for (int m = 0; m < 4; ++m) {                                       \
                int row = wr * 64 + m * 16 + rlow;                              \
                int sl = rgrp ^ ((row >> 1) & 3);                               \
                af[m] = *(const long2v*)&As[tt * 8192 + row * 64 + sl * 16];    \
            }                                                                   \
            _Pragma("unroll")                                                   \
            for (int n = 0; n < 4; ++n) {                                       \
                int col = wc * 64 + n * 16 + rlow;                              \
                int sl = rgrp ^ ((col >> 1) & 3);                               \
                bf[n] = *(const long2v*)&Bs[tt * 8192 + col * 64 + sl * 16];    \
            }                                                                   \
            __builtin_amdgcn_s_setprio(1);                                      \
            _Pragma("unroll")                                                   \
            for (int m = 0; m < 4; ++m)                                         \
                _Pragma("unroll")                                               \
                for (int n = 0; n < 4; ++n) {                                   \
                    acc_[m][n] = __builtin_amdgcn_mfma_f32_16x16x32_fp8_fp8(    \
                        af[m][0], bf[n][0], acc_[m][n], 0, 0, 0);               \
                    acc_[m][n] = __builtin_amdgcn_mfma_f32_16x16x32_fp8_fp8(    \
                        af[m][1], bf[n][1], acc_[m][n], 0, 0, 0);               \
                }                                                               \
            __builtin_amdgcn_s_setprio(0);                                      \
        }

    int I, J;
    int tb = blockIdx.x;
    if (tb >= NTRI) return;
    DECODE(tb, I, J);
    int rowA = I * 128, rowB = J * 128;
    STAGE(0, 3, rowA, rowB);           // first tile's prologue (only exposed one)

    while (true) {
        // r-vector staging for this tile (safe: previous epilogue done)
        if (tid < 128) rIl[tid] = rvec[rowA + tid];
        else           rJl[tid - 128] = rvec[rowB + (tid - 128)];
        __syncthreads();               // chunk0-2 + rIl/rJl ready

        f32x4 acc_[4][4] = {};
        COMPUTE(3);
        __syncthreads();               // reads of chunk0-2 done
        STAGE(3, 2, rowA, rowB);
        __syncthreads();               // chunk3-4 ready
        COMPUTE(2);
        __syncthreads();               // all As/Bs reads done

        // issue NEXT tile's chunk0-2 stage under the epilogue
        int tbn = tb + PERS;
        int In, Jn, rowAn = 0, rowBn = 0;
        if (tbn < NTRI) {
            DECODE(tbn, In, Jn);
            rowAn = In * 128; rowBn = Jn * 128;
            STAGE(0, 3, rowAn, rowBn);
        }

        // epilogue: K_ij = exp(2*dot - r_i - r_j)
        float psum = 0.f;
        #pragma unroll
        for (int m = 0; m < 4; ++m) {
            float ri[4];
            #pragma unroll
            for (int j = 0; j < 4; ++j) ri[j] = rIl[wr * 64 + m * 16 + rgrp * 4 + j];
            #pragma unroll
            for (int n = 0; n < 4; ++n) {
                float rj = rJl[wc * 64 + n * 16 + rlow];
                f32x4 a = acc_[m][n];
                psum += __expf(2.f * a.x - ri[0] - rj);
                psum += __expf(2.f * a.y - ri[1] - rj);
                psum += __expf(2.f * a.z - ri[2] - rj);
                psum += __expf(2.f * a.w - ri[3] - rj);
            }
        }
        #pragma unroll
        for (int o = 32; o; o >>= 1) psum += __shfl_xor(psum, o, 64);
        if (lane == 0) wsum[wv] = psum;
        __syncthreads();               // wsum ready; rIl/rJl reads done
        if (tid == 0) {
            float bs = wsum[0] + wsum[1] + wsum[2] + wsum[3];
            double sgn = ((I < 32) == (J < 32)) ? 1.0 : -1.0;
            double fac = (I == J) ? 1.0 : 2.0;
            blocksum[tb] = sgn * fac * (double)bs;
        }

        if (tbn >= NTRI) break;
        tb = tbn; I = In; J = Jn; rowA = rowAn; rowB = rowBn;
    }
}

// ---------------- K5: finalize (reduce 2080 block sums) ----------------------
__global__ __launch_bounds__(256) void k_final(
    const double* __restrict__ blocksum, float* __restrict__ out) {
    __shared__ double sh[4];
    int t = threadIdx.x, wv = t >> 6, lane = t & 63;
    double s = 0.0;
    for (int i = t; i < NTRI; i += 256) s += blocksum[i];
    #pragma unroll
    for (int o = 32; o; o >>= 1) s += __shfl_xor(s, o, 64);
    if (lane == 0) sh[wv] = s;
    __syncthreads();
    if (t == 0) {
        double tot = sh[0] + sh[1] + sh[2] + sh[3];
        out[0] = (float)(tot / ((double)B_ROWS * (double)B_ROWS));
    }
}

extern "C" void kernel_launch(void* const* d_in, const int* in_sizes, int n_in,
                              void* d_out, int out_size, void* d_ws, size_t ws_size,
                              hipStream_t stream) {
    const float* s0 = (const float*)d_in[0];
    const float* s1 = (const float*)d_in[1];
    const float* t0 = (const float*)d_in[2];
    const float* t1 = (const float*)d_in[3];
    char* ws = (char*)d_ws;
    float*  gam  = (float*)(ws + OFF_GAM);
    float*  pq0  = (float*)(ws + OFF_PQ0);
    float*  pq1  = (float*)(ws + OFF_PQ1);
    float*  p0   = (float*)(ws + OFF_P0);
    float*  p1   = (float*)(ws + OFF_P1);
    float*  rvec = (float*)(ws + OFF_R);
    double* bsum = (double*)(ws + OFF_BSUM);
    unsigned char* phi = (unsigned char*)(ws + OFF_PHI);

    k_stats<<<NSB, 256, 0, stream>>>(s0, s1, t0, t1, p0, p1, pq0, pq1);
    k_gamma<<<1, 256, 0, stream>>>(pq0, pq1, p0, p1, gam);
    k_pack<<<2048, 256, 0, stream>>>(s0, s1, t0, t1, gam, phi, rvec);
    k_mmd<<<PERS, 256, 0, stream>>>(phi, rvec, bsum);
    k_final<<<1, 256, 0, stream>>>(bsum, (float*)d_out);
}